// Round 13
// baseline (364.364 us; speedup 1.0000x reference)
//
#include <hip/hip_runtime.h>
#include <math.h>

// Problem constants
#define B_   32
#define T0_  256
#define J_   512
#define V_   1024
#define Q_   32
#define L_   20
#define P_   241
#define NEG_ (-1e9f)

typedef __attribute__((ext_vector_type(8))) _Float16 half8;
typedef __attribute__((ext_vector_type(4))) _Float16 half4v;
typedef __attribute__((ext_vector_type(4))) float f32x4;

// ---------------------------------------------------------------------------
// 1-pass fp16 MFMA GEMM: C[m][n] = sum_k AH[m][k] * BH[n][k]
// R10-proven config (204us): tile 64x64, 4 waves (2x2), wave tile 32x32,
// KCH=128, A AND B staged in LDS (R12 lesson: B-direct fragment loads are
// uncoalesced 16-row-strided 16B reads -> 5x HBM overfetch. B stays in LDS).
// Grids >= 2-4 blocks/CU (R3/R5/R9/R11 lessons: occupancy beats per-wave
// efficiency in this small-K latency-bound regime).
// blockIdx.x = COLUMN block (fastest) for A-panel L2 sharing.
// A row view: arow = (m/TDIV)*SB + S0 + (m%TDIV)*TMUL, row stride ASTR
// (im2col for stride-2 conv: TMUL=2, ASTR=512).
// EPI: 0 = +bias -> fp16 (orow map); 1 = +bias+relu -> fp16;
//      2 = plain f32 (stride NS); 4 = split-K partials + FUSED last-block
//      reduction (CK-style): write f32 partial [z][MP][512], threadfence,
//      ticket via device-scope atomicAdd(cntp[tile]); last block re-reads
//      all gridDim.z partials in FIXED z order (bit-identical to a separate
//      reduce kernel), +bias+relu -> fp16, resets counter to 0.
// LDS row stride KCH+8 halves: uniform bank spread on b128 ops.
// Staging: static register arrays, fixed plane pointers (R6 scratch lesson).
// ---------------------------------------------------------------------------
template<int BM, int KCH, int EPI>
__global__ __launch_bounds__(256) void g1p(
    const _Float16* __restrict__ AH, const _Float16* __restrict__ BH,
    const float* __restrict__ bias,
    _Float16* __restrict__ outH, float* __restrict__ outF, int* cntp,
    int MROWS, int TDIV, int SB, int S0, int TMUL, int ASTR, int BSTR,
    int KLEN, int MP, int OSB, int OS0, int NS) {
  constexpr int FM = BM / 32;
  constexpr int LSTR = KCH + 8;
  constexpr int TPRA = 256 / BM;
  constexpr int AW = KCH / TPRA;
  constexpr int AU = AW / 8;
  constexpr int BW = KCH / 4;
  constexpr int BU = BW / 8;
  __shared__ _Float16 aS[BM * LSTR], bS[64 * LSTR];
  __shared__ int lastFlag;

  const int tid = threadIdx.x;
  const int n0 = blockIdx.x * 64, m0 = blockIdx.y * BM;   // x = column block
  const int k00 = blockIdx.z * KLEN;
  const int wave = tid >> 6, lane = tid & 63;
  const int wm = (wave >> 1) * (BM / 2), wn = (wave & 1) * 32;
  const int fr = lane & 15, fq = lane >> 4;

  const int arow = tid / TPRA, acol = (tid % TPRA) * AW;
  const int brow = tid >> 2, bcol = (tid & 3) * BW;

  const int gm = m0 + arow;
  const bool mval = gm < MROWS;
  const int b2g = gm / TDIV, t2g = gm - b2g * TDIV;
  const size_t aoff = (size_t)(b2g * SB + S0 + t2g * TMUL) * (size_t)ASTR;
  const size_t boff = (size_t)(n0 + brow) * (size_t)BSTR;

  f32x4 acc[FM][2];
  #pragma unroll
  for (int i = 0; i < FM; ++i) { acc[i][0] = (f32x4)0.f; acc[i][1] = (f32x4)0.f; }

  half8 z;
  #pragma unroll
  for (int j = 0; j < 8; ++j) z[j] = (_Float16)0.f;

  half8 rA[AU], rB[BU];
  auto load = [&](int it) {
    const int k = k00 + it * KCH;
    if (mval) {
      #pragma unroll
      for (int i = 0; i < AU; ++i)
        rA[i] = *reinterpret_cast<const half8*>(&AH[aoff + k + acol + i * 8]);
    } else {
      #pragma unroll
      for (int i = 0; i < AU; ++i) rA[i] = z;
    }
    #pragma unroll
    for (int i = 0; i < BU; ++i)
      rB[i] = *reinterpret_cast<const half8*>(&BH[boff + k + bcol + i * 8]);
  };

  load(0);
  const int NI = KLEN / KCH;

  for (int it = 0; it < NI; ++it) {
    __syncthreads();
    #pragma unroll
    for (int i = 0; i < AU; ++i)
      *reinterpret_cast<half8*>(&aS[arow * LSTR + acol + i * 8]) = rA[i];
    #pragma unroll
    for (int i = 0; i < BU; ++i)
      *reinterpret_cast<half8*>(&bS[brow * LSTR + bcol + i * 8]) = rB[i];
    __syncthreads();
    if (it + 1 < NI) load(it + 1);

    #pragma unroll
    for (int ks = 0; ks < KCH / 32; ++ks) {
      const int ko = ks * 32 + fq * 8;
      half8 a[FM], b[2];
      #pragma unroll
      for (int mt = 0; mt < FM; ++mt)
        a[mt] = *reinterpret_cast<const half8*>(&aS[(wm + mt * 16 + fr) * LSTR + ko]);
      b[0] = *reinterpret_cast<const half8*>(&bS[(wn + fr) * LSTR + ko]);
      b[1] = *reinterpret_cast<const half8*>(&bS[(wn + 16 + fr) * LSTR + ko]);
      #pragma unroll
      for (int mt = 0; mt < FM; ++mt) {
        acc[mt][0] = __builtin_amdgcn_mfma_f32_16x16x32_f16(a[mt], b[0], acc[mt][0], 0, 0, 0);
        acc[mt][1] = __builtin_amdgcn_mfma_f32_16x16x32_f16(a[mt], b[1], acc[mt][1], 0, 0, 0);
      }
    }
  }

  // Epilogue. C layout: col = lane&15 (n), row = fq*4 + reg (m).
  #pragma unroll
  for (int mt = 0; mt < FM; ++mt) {
    const int mB2 = m0 + wm + mt * 16 + fq * 4;
    #pragma unroll
    for (int nt = 0; nt < 2; ++nt) {
      const int n = n0 + wn + nt * 16 + fr;
      f32x4 c = acc[mt][nt];
      #pragma unroll
      for (int r = 0; r < 4; ++r) {
        const int m = mB2 + r;
        if (m < MROWS) {
          if (EPI == 3 || EPI == 4) {
            outF[((size_t)blockIdx.z * MP + m) * 512 + n] = c[r];
          } else if (EPI == 2) {
            outF[(size_t)m * NS + n] = c[r];
          } else {
            float x = c[r] + bias[n];
            if (EPI == 1) x = fmaxf(x, 0.f);
            const int bb2 = m / TDIV, tt2 = m - bb2 * TDIV;
            const int orow = bb2 * OSB + OS0 + tt2;
            outH[(size_t)orow * 512 + n] = (_Float16)x;
          }
        }
      }
    }
  }

  if (EPI == 4) {
    // Fused split-K reduction, last-block pattern. Tiles are exact (MROWS
    // multiple of 64 for all conv layers), so no m guard needed here.
    const int tileId = blockIdx.y * gridDim.x + blockIdx.x;
    const int kS = gridDim.z;
    __threadfence();                              // release my partials
    if (tid == 0) {
      int old = atomicAdd(&cntp[tileId], 1);
      lastFlag = (old == kS - 1);
    }
    __syncthreads();
    if (lastFlag) {
      __threadfence();                            // acquire others' partials
      const int mr = m0 + (tid >> 2);
      const int nc = n0 + (tid & 3) * 16;
      float s[16];
      #pragma unroll
      for (int j = 0; j < 16; ++j) s[j] = 0.f;
      for (int zz = 0; zz < kS; ++zz) {           // FIXED order: deterministic
        const float* p = &outF[((size_t)zz * MP + mr) * 512 + nc];
        #pragma unroll
        for (int g = 0; g < 4; ++g) {
          float4 v = *reinterpret_cast<const float4*>(p + g * 4);
          s[g * 4 + 0] += v.x; s[g * 4 + 1] += v.y;
          s[g * 4 + 2] += v.z; s[g * 4 + 3] += v.w;
        }
      }
      const int bb2 = mr / TDIV, tt2 = mr - bb2 * TDIV;
      const int orow = bb2 * OSB + OS0 + tt2;
      half8 o0, o1;
      #pragma unroll
      for (int j = 0; j < 8; ++j) {
        o0[j] = (_Float16)fmaxf(s[j] + bias[nc + j], 0.f);
        o1[j] = (_Float16)fmaxf(s[8 + j] + bias[nc + 8 + j], 0.f);
      }
      *reinterpret_cast<half8*>(&outH[(size_t)orow * 512 + nc]) = o0;
      *reinterpret_cast<half8*>(&outH[(size_t)orow * 512 + nc + 8]) = o1;
      if (tid == 0) cntp[tileId] = 0;             // self-restore for next layer
    }
  }
}

// ---------------------------------------------------------------------------
// Unified prep. Sections (grid-stride over units):
//   [0,C0): video cvt f4      [C0,C1): fc_w cvt   [C1,C2): pw cvt
//   [C2,C3): words cvt        [C3,C4): conv_w repack (coalesced transpose)
//   [C4,C5): zero split-K ticket counters (256 ints)
// ---------------------------------------------------------------------------
#define PREP_C0 2097152
#define PREP_C1 2228224
#define PREP_C2 2293760
#define PREP_C3 2375680
#define PREP_C4 2768896
#define PREP_C5 2768960
__global__ __launch_bounds__(256) void prep_kernel(
    const float* __restrict__ video, const float* __restrict__ fcw,
    const float* __restrict__ pw, const float* __restrict__ words,
    const float* __restrict__ cw,
    _Float16* __restrict__ videoH, _Float16* __restrict__ fcwH,
    _Float16* __restrict__ pwH, _Float16* __restrict__ wordsH,
    _Float16* __restrict__ cwH, int* __restrict__ cnt) {
  for (int u = blockIdx.x * 256 + threadIdx.x; u < PREP_C5; u += 2048 * 256) {
    if (u < PREP_C3) {
      const float* src; _Float16* dst; int off;
      if (u < PREP_C0)      { src = video; dst = videoH; off = u; }
      else if (u < PREP_C1) { src = fcw;   dst = fcwH;   off = u - PREP_C0; }
      else if (u < PREP_C2) { src = pw;    dst = pwH;    off = u - PREP_C1; }
      else                  { src = words; dst = wordsH; off = u - PREP_C2; }
      float4 v = *reinterpret_cast<const float4*>(&src[(size_t)off * 4]);
      half4v h;
      h[0] = (_Float16)v.x; h[1] = (_Float16)v.y;
      h[2] = (_Float16)v.z; h[3] = (_Float16)v.w;
      *reinterpret_cast<half4v*>(&dst[(size_t)off * 4]) = h;
    } else if (u < PREP_C4) {
      int e = u - PREP_C3;                 // (li, o, i4)
      int li = e >> 16, rem = e & 65535, o = rem >> 7, i4 = rem & 127;
      size_t srcbase = ((size_t)(li * 512 + o) * 512 + i4 * 4) * 4;
      float4 v0 = *reinterpret_cast<const float4*>(&cw[srcbase]);
      float4 v1 = *reinterpret_cast<const float4*>(&cw[srcbase + 4]);
      float4 v2 = *reinterpret_cast<const float4*>(&cw[srcbase + 8]);
      float4 v3 = *reinterpret_cast<const float4*>(&cw[srcbase + 12]);
      size_t rb = ((size_t)(li * 512 + o)) * 2048 + i4 * 4;
      half4v h;
      h[0] = (_Float16)v0.x; h[1] = (_Float16)v1.x; h[2] = (_Float16)v2.x; h[3] = (_Float16)v3.x;
      *reinterpret_cast<half4v*>(&cwH[rb]) = h;
      h[0] = (_Float16)v0.y; h[1] = (_Float16)v1.y; h[2] = (_Float16)v2.y; h[3] = (_Float16)v3.y;
      *reinterpret_cast<half4v*>(&cwH[rb + 512]) = h;
      h[0] = (_Float16)v0.z; h[1] = (_Float16)v1.z; h[2] = (_Float16)v2.z; h[3] = (_Float16)v3.z;
      *reinterpret_cast<half4v*>(&cwH[rb + 1024]) = h;
      h[0] = (_Float16)v0.w; h[1] = (_Float16)v1.w; h[2] = (_Float16)v2.w; h[3] = (_Float16)v3.w;
      *reinterpret_cast<half4v*>(&cwH[rb + 1536]) = h;
    } else {
      int e = u - PREP_C4;                 // zero 256 counters (4 ints/unit)
      *reinterpret_cast<int4*>(&cnt[e * 4]) = make_int4(0, 0, 0, 0);
    }
  }
}

// ---------------------------------------------------------------------------
// Merged fnorm + gram: blocks 0..31 = per-query word Gram; blocks 32..1959 =
// row L2 norms of f_all (wave per row).
// ---------------------------------------------------------------------------
__global__ __launch_bounds__(256) void fng_kernel(
    const float* __restrict__ words, const _Float16* __restrict__ fH,
    float* __restrict__ gram, float* __restrict__ fn) {
  __shared__ float wsh[L_][513];
  const int bid = blockIdx.x, tid = threadIdx.x;
  if (bid < 32) {
    const int q = bid;
    for (int idx = tid; idx < L_ * 512; idx += 256)
      wsh[idx >> 9][idx & 511] = words[(size_t)q * L_ * J_ + idx];
    __syncthreads();
    for (int pr = tid; pr < L_ * L_; pr += 256) {
      int l = pr / L_, l2 = pr % L_;
      float sum = 0.f;
      for (int d = 0; d < J_; ++d) sum += wsh[l][d] * wsh[l2][d];
      gram[q * L_ * L_ + pr] = sum;
    }
  } else {
    const int gw = (bid - 32) * 4 + (tid >> 6);
    const int lane = tid & 63;
    if (gw >= B_ * P_) return;
    half8 h = *reinterpret_cast<const half8*>(&fH[(size_t)gw * 512 + lane * 8]);
    float s = 0.f;
    #pragma unroll
    for (int j = 0; j < 8; ++j) {
      float x = (float)h[j];
      s += x * x;
    }
    #pragma unroll
    for (int off = 32; off; off >>= 1) s += __shfl_xor(s, off);
    if (lane == 0) fn[gw] = sqrtf(s);
  }
}

// ---------------------------------------------------------------------------
// Softmax + cosine-sim epilogue per (q,b,p); positive_map fused (q==b rows).
// ---------------------------------------------------------------------------
__global__ __launch_bounds__(256) void sim_kernel(
    const float* __restrict__ logits, const float* __restrict__ gram,
    const float* __restrict__ fnorm, float* __restrict__ score,
    float* __restrict__ out) {
  int idx = blockIdx.x * 256 + threadIdx.x;
  if (idx >= Q_ * B_ * P_) return;
  int q = idx / (B_ * P_);
  int r = idx - q * (B_ * P_);
  const float* lg = &logits[(size_t)r * (Q_ * L_) + q * L_];
  float raw[L_], e[L_];
  float m = -1e30f;
  #pragma unroll
  for (int l = 0; l < L_; ++l) { raw[l] = lg[l]; m = fmaxf(m, raw[l]); }
  float s = 0.f;
  #pragma unroll
  for (int l = 0; l < L_; ++l) { e[l] = __expf(raw[l] - m); s += e[l]; }
  float inv = 1.f / s;
  float fvs = 0.f;
  #pragma unroll
  for (int l = 0; l < L_; ++l) fvs += e[l] * raw[l];
  fvs *= inv;
  const float* G = &gram[q * L_ * L_];
  float vn2 = 0.f;
  for (int l = 0; l < L_; ++l) {
    float acc = 0.f;
    #pragma unroll
    for (int l2 = 0; l2 < L_; ++l2) acc += e[l2] * G[l * L_ + l2];
    vn2 += e[l] * acc;
  }
  vn2 *= inv * inv;
  float fn = fnorm[r] + 1e-8f;
  float vn = sqrtf(fmaxf(vn2, 0.f)) + 1e-8f;
  float val = fvs / (fn * vn);
  score[idx] = val;
  int b = r / P_;
  if (b == q) out[1 + r] = val;   // positive_map (r = b*P + p)
}

// ---------------------------------------------------------------------------
// Greedy NMS
// ---------------------------------------------------------------------------
__global__ __launch_bounds__(256) void nms_kernel(
    const float* __restrict__ score, const float* __restrict__ iou,
    const float* __restrict__ lam, float* __restrict__ smat) {
  int wid = (blockIdx.x * 256 + threadIdx.x) >> 6;
  int lane = threadIdx.x & 63;
  if (wid >= Q_ * B_) return;
  const float* srow = &score[(size_t)wid * P_];
  float s[4];
  #pragma unroll
  for (int i = 0; i < 4; ++i) {
    int p = lane + 64 * i;
    s[i] = (p < P_) ? srow[p] : NEG_;
  }
  float lamv = lam[0];
  float acc = 0.f, wgt = 1.f;
  for (int k = 0; k < 5; ++k) {
    float bv = NEG_ * 2.f; int bi = 1 << 30;
    #pragma unroll
    for (int i = 0; i < 4; ++i) {
      int p = lane + 64 * i;
      if (s[i] > bv) { bv = s[i]; bi = p; }
    }
    for (int off = 32; off; off >>= 1) {
      float ov = __shfl_xor(bv, off);
      int oi = __shfl_xor(bi, off);
      if (ov > bv || (ov == bv && oi < bi)) { bv = ov; bi = oi; }
    }
    acc += bv * wgt;
    wgt *= lamv;
    const float* irow = &iou[(size_t)bi * P_];
    #pragma unroll
    for (int i = 0; i < 4; ++i) {
      int p = lane + 64 * i;
      if (p < P_ && irow[p] > 0.7f) s[i] = NEG_;
      if (p == bi) s[i] = NEG_;
    }
  }
  if (lane == 0) smat[wid] = acc * 0.2f;
}

// ---------------------------------------------------------------------------
// diag margin loss
// ---------------------------------------------------------------------------
__global__ __launch_bounds__(1024) void loss_kernel(
    const float* __restrict__ smat, float* __restrict__ out) {
  __shared__ float sm[B_][B_ + 1];
  __shared__ float red[16];
  int tid = threadIdx.x;
  sm[tid >> 5][tid & 31] = smat[tid];
  __syncthreads();
  int i = tid >> 5, j = tid & 31;
  float val = 0.f;
  if (i != j) {
    float sij = sm[i][j];
    val = fmaxf(0.f, 0.2f + sij - sm[i][i]) + fmaxf(0.f, 0.2f + sij - sm[j][j]);
  }
  #pragma unroll
  for (int off = 32; off; off >>= 1) val += __shfl_xor(val, off);
  if ((tid & 63) == 0) red[tid >> 6] = val;
  __syncthreads();
  if (tid == 0) {
    float t = 0.f;
    #pragma unroll
    for (int w = 0; w < 16; ++w) t += red[w];
    out[0] = t / 32.f;
  }
}

extern "C" void kernel_launch(void* const* d_in, const int* in_sizes, int n_in,
                              void* d_out, int out_size, void* d_ws, size_t ws_size,
                              hipStream_t stream) {
  const float* video  = (const float*)d_in[0];
  const float* words  = (const float*)d_in[1];
  // d_in[2] = w_masks: all-ones by construction, unused
  const float* lam    = (const float*)d_in[3];
  const float* iou    = (const float*)d_in[4];
  const float* fc_w   = (const float*)d_in[5];
  const float* fc_b   = (const float*)d_in[6];
  const float* conv_w = (const float*)d_in[7];
  const float* conv_b = (const float*)d_in[8];
  const float* pw     = (const float*)d_in[9];
  const float* pb     = (const float*)d_in[10];
  float* out = (float*)d_out;

  // Workspace layout (bytes) — R10 footprint + 1KB ticket counters.
  // Split-K partials alias the logits region (written later).
  char* base = (char*)d_ws;
  _Float16* videoH= (_Float16*)(base + 0);              // 8192*1024 (16.78 MB)
  _Float16* fcoH  = (_Float16*)(base + 16777216);       // 8192*512  (8.39 MB)
  _Float16* pyrH  = (_Float16*)(base + 25165824);       // 7712*512  (7.90 MB)
  _Float16* fallH = (_Float16*)(base + 33062912);       // 7712*512  (7.90 MB)
  _Float16* cwH   = (_Float16*)(base + 40960000);       // 6*512*2048 (12.58 MB)
  _Float16* fcwH  = (_Float16*)(base + 53542912);       // 512*1024  (1.05 MB)
  _Float16* pwH   = (_Float16*)(base + 54591488);       // 512*512   (0.52 MB)
  _Float16* wordsH= (_Float16*)(base + 55115776);       // 32*20*512 (0.66 MB)
  float*    logits= (float*)(base + 55771136);          // 7712*640 f32 (19.74 MB)
  float*    part  = (float*)(base + 55771136);          //   alias, max 8.12 MB
  float*    score = (float*)(base + 75513856);          // 246784 f32
  float*    fnorm = (float*)(base + 76500992);          // 7936 f32
  float*    gram  = (float*)(base + 76532736);          // 12800 f32
  float*    smat  = (float*)(base + 76583936);          // 1024 f32
  int*      cnt   = (int*)(base + 76588032);            // 256 ints (tickets)

  const int Tl[6]   = {127, 62, 30, 14, 6, 2};
  const int Poff[6] = {0, 127, 189, 219, 233, 239};

  // 0) unified operand prep + counter zeroing (1 launch)
  prep_kernel<<<2048, 256, 0, stream>>>(
      video, fc_w, pw, words, conv_w, videoH, fcwH, pwH, wordsH, cwH, cnt);

  // 1) FC: M=8192 N=512 K=1024, grid (8,128) = 1024 blocks (4/CU)
  g1p<64, 128, 0><<<dim3(8, 128), 256, 0, stream>>>(
      videoH, fcwH, fc_b, fcoH, nullptr, nullptr,
      8192, 8192, 0, 0, 1, 1024, 1024, 1024, 0, 0, 0, 512);

  // 2) conv0: M=4064 K=2048, grid (8,64) = 512 blocks, direct write
  g1p<64, 128, 1><<<dim3(8, 64, 1), 256, 0, stream>>>(
      fcoH, cwH, conv_b, pyrH, nullptr, nullptr,
      4064, 127, 256, 0, 2, 512, 2048, 2048, 0, P_, 0, 512);

  // 3) conv1..5: split-K with FUSED last-block reduction (no reduce launches)
  const int Ms[5]    = {1984, 960, 448, 192, 64};
  const int mbs[5]   = {31, 15, 7, 3, 1};
  const int kSs[5]   = {2, 4, 4, 8, 8};
  const int KLENs[5] = {1024, 512, 512, 256, 256};
  for (int i = 0; i < 5; ++i) {
    int li = i + 1;
    g1p<64, 128, 4><<<dim3(8, mbs[i], kSs[i]), 256, 0, stream>>>(
        pyrH, cwH + (size_t)li * 512 * 2048, conv_b + li * 512, pyrH, part, cnt,
        Ms[i], Tl[li], P_, Poff[li - 1], 2, 512, 2048, KLENs[i], Ms[i],
        P_, Poff[li], 512);
  }

  // 4) pointwise projection: M=7712 N=512 K=512, grid (8,121) = 968 blocks
  g1p<64, 128, 0><<<dim3(8, 121, 1), 256, 0, stream>>>(
      pyrH, pwH, pb, fallH, nullptr, nullptr,
      B_ * P_, B_ * P_, 0, 0, 1, 512, 512, 512, 0, 0, 0, 512);

  // 5) merged gram + fnorm (1 launch)
  fng_kernel<<<1960, 256, 0, stream>>>(words, fallH, gram, fnorm);

  // 6) attention logits: N=640, grid (10,121) = 1210 blocks
  g1p<64, 128, 2><<<dim3(10, 121, 1), 256, 0, stream>>>(
      fallH, wordsH, nullptr, nullptr, logits, nullptr,
      B_ * P_, B_ * P_, 0, 0, 1, 512, 512, 512, 0, 0, 0, 640);

  // 7) softmax + cosine similarity (+ fused positive_map)
  sim_kernel<<<964, 256, 0, stream>>>(logits, gram, fnorm, score, out);

  // 8) NMS, loss
  nms_kernel<<<256, 256, 0, stream>>>(score, iou, lam, smat);
  loss_kernel<<<1, 1024, 0, stream>>>(smat, out);
}

// Round 14
// 188.591 us; speedup vs baseline: 1.9320x; 1.9320x over previous
//
#include <hip/hip_runtime.h>
#include <math.h>

// Problem constants
#define B_   32
#define T0_  256
#define J_   512
#define V_   1024
#define Q_   32
#define L_   20
#define P_   241
#define NEG_ (-1e9f)

typedef __attribute__((ext_vector_type(8))) _Float16 half8;
typedef __attribute__((ext_vector_type(4))) _Float16 half4v;
typedef __attribute__((ext_vector_type(4))) float f32x4;

// ---------------------------------------------------------------------------
// 1-pass fp16 MFMA GEMM: C[m][n] = sum_k AH[m][k] * BH[n][k]
// R10-proven config (204us): tile 64x64, 4 waves (2x2), wave tile 32x32,
// KCH=128, A AND B staged in LDS. Lessons baked in:
//  - R3/R5/R9/R11: occupancy beats per-wave efficiency (keep grids >=2-4
//    blocks/CU; 64x64 tile, never larger).
//  - R12: B-direct fragment loads shred cachelines (5x overfetch) — B in LDS.
//  - R13: NO per-block device-scope fences (threadfence = cross-XCD L2
//    storm, 92us/dispatch). Split-K reduction stays a separate launch.
// blockIdx.x = COLUMN block (fastest) for A-panel L2 sharing.
// A row view: arow = (m/TDIV)*SB + S0 + (m%TDIV)*TMUL, row stride ASTR
// (im2col for stride-2 conv: TMUL=2, ASTR=512).
// EPI: 0 = +bias -> fp16 (orow map); 1 = +bias+relu -> fp16;
//      2 = plain f32 (stride NS); 3 = f32 partials [z][MP][512].
// LDS row stride KCH+8 halves. Static register staging (R6 scratch lesson).
// ---------------------------------------------------------------------------
template<int BM, int KCH, int EPI>
__global__ __launch_bounds__(256) void g1p(
    const _Float16* __restrict__ AH, const _Float16* __restrict__ BH,
    const float* __restrict__ bias,
    _Float16* __restrict__ outH, float* __restrict__ outF,
    int MROWS, int TDIV, int SB, int S0, int TMUL, int ASTR, int BSTR,
    int KLEN, int MP, int OSB, int OS0, int NS) {
  constexpr int FM = BM / 32;
  constexpr int LSTR = KCH + 8;
  constexpr int TPRA = 256 / BM;
  constexpr int AW = KCH / TPRA;
  constexpr int AU = AW / 8;
  constexpr int BW = KCH / 4;
  constexpr int BU = BW / 8;
  __shared__ _Float16 aS[BM * LSTR], bS[64 * LSTR];

  const int tid = threadIdx.x;
  const int n0 = blockIdx.x * 64, m0 = blockIdx.y * BM;   // x = column block
  const int k00 = blockIdx.z * KLEN;
  const int wave = tid >> 6, lane = tid & 63;
  const int wm = (wave >> 1) * (BM / 2), wn = (wave & 1) * 32;
  const int fr = lane & 15, fq = lane >> 4;

  const int arow = tid / TPRA, acol = (tid % TPRA) * AW;
  const int brow = tid >> 2, bcol = (tid & 3) * BW;

  const int gm = m0 + arow;
  const bool mval = gm < MROWS;
  const int b2g = gm / TDIV, t2g = gm - b2g * TDIV;
  const size_t aoff = (size_t)(b2g * SB + S0 + t2g * TMUL) * (size_t)ASTR;
  const size_t boff = (size_t)(n0 + brow) * (size_t)BSTR;

  f32x4 acc[FM][2];
  #pragma unroll
  for (int i = 0; i < FM; ++i) { acc[i][0] = (f32x4)0.f; acc[i][1] = (f32x4)0.f; }

  half8 z;
  #pragma unroll
  for (int j = 0; j < 8; ++j) z[j] = (_Float16)0.f;

  half8 rA[AU], rB[BU];
  auto load = [&](int it) {
    const int k = k00 + it * KCH;
    if (mval) {
      #pragma unroll
      for (int i = 0; i < AU; ++i)
        rA[i] = *reinterpret_cast<const half8*>(&AH[aoff + k + acol + i * 8]);
    } else {
      #pragma unroll
      for (int i = 0; i < AU; ++i) rA[i] = z;
    }
    #pragma unroll
    for (int i = 0; i < BU; ++i)
      rB[i] = *reinterpret_cast<const half8*>(&BH[boff + k + bcol + i * 8]);
  };

  load(0);
  const int NI = KLEN / KCH;

  for (int it = 0; it < NI; ++it) {
    __syncthreads();
    #pragma unroll
    for (int i = 0; i < AU; ++i)
      *reinterpret_cast<half8*>(&aS[arow * LSTR + acol + i * 8]) = rA[i];
    #pragma unroll
    for (int i = 0; i < BU; ++i)
      *reinterpret_cast<half8*>(&bS[brow * LSTR + bcol + i * 8]) = rB[i];
    __syncthreads();
    if (it + 1 < NI) load(it + 1);

    #pragma unroll
    for (int ks = 0; ks < KCH / 32; ++ks) {
      const int ko = ks * 32 + fq * 8;
      half8 a[FM], b[2];
      #pragma unroll
      for (int mt = 0; mt < FM; ++mt)
        a[mt] = *reinterpret_cast<const half8*>(&aS[(wm + mt * 16 + fr) * LSTR + ko]);
      b[0] = *reinterpret_cast<const half8*>(&bS[(wn + fr) * LSTR + ko]);
      b[1] = *reinterpret_cast<const half8*>(&bS[(wn + 16 + fr) * LSTR + ko]);
      #pragma unroll
      for (int mt = 0; mt < FM; ++mt) {
        acc[mt][0] = __builtin_amdgcn_mfma_f32_16x16x32_f16(a[mt], b[0], acc[mt][0], 0, 0, 0);
        acc[mt][1] = __builtin_amdgcn_mfma_f32_16x16x32_f16(a[mt], b[1], acc[mt][1], 0, 0, 0);
      }
    }
  }

  // Epilogue. C layout: col = lane&15 (n), row = fq*4 + reg (m).
  #pragma unroll
  for (int mt = 0; mt < FM; ++mt) {
    const int mB2 = m0 + wm + mt * 16 + fq * 4;
    #pragma unroll
    for (int nt = 0; nt < 2; ++nt) {
      const int n = n0 + wn + nt * 16 + fr;
      f32x4 c = acc[mt][nt];
      #pragma unroll
      for (int r = 0; r < 4; ++r) {
        const int m = mB2 + r;
        if (m < MROWS) {
          if (EPI == 3) {
            outF[((size_t)blockIdx.z * MP + m) * 512 + n] = c[r];
          } else if (EPI == 2) {
            outF[(size_t)m * NS + n] = c[r];
          } else {
            float x = c[r] + bias[n];
            if (EPI == 1) x = fmaxf(x, 0.f);
            const int bb2 = m / TDIV, tt2 = m - bb2 * TDIV;
            const int orow = bb2 * OSB + OS0 + tt2;
            outH[(size_t)orow * 512 + n] = (_Float16)x;
          }
        }
      }
    }
  }
}

// ---------------------------------------------------------------------------
// Split-K reduce: out(orow) = relu(sum_z part[z][m] + bias) -> fp16
// (separate launch on purpose — stream ordering is the cheap global fence)
// ---------------------------------------------------------------------------
__global__ __launch_bounds__(256) void reduce_kernel(
    const float* __restrict__ part, const float* __restrict__ bias,
    _Float16* __restrict__ outH,
    int kS, int MROWS, int MP, int Tl, int Poff) {
  int idx = blockIdx.x * 256 + threadIdx.x;
  if (idx >= MROWS * 512) return;
  int m = idx >> 9, n = idx & 511;
  float s = 0.f;
  for (int ks = 0; ks < kS; ++ks) s += part[((size_t)ks * MP + m) * 512 + n];
  float x = fmaxf(s + bias[n], 0.f);
  int b2 = m / Tl, t2 = m - b2 * Tl;
  int orow = b2 * P_ + Poff + t2;
  outH[(size_t)orow * 512 + n] = (_Float16)x;
}

// ---------------------------------------------------------------------------
// Unified prep. Sections (grid-stride over units):
//   [0,C0): video cvt f4      [C0,C1): fc_w cvt   [C1,C2): pw cvt
//   [C2,C3): words cvt        [C3,C4): conv_w repack (coalesced transpose)
// ---------------------------------------------------------------------------
#define PREP_C0 2097152
#define PREP_C1 2228224
#define PREP_C2 2293760
#define PREP_C3 2375680
#define PREP_C4 2768896
__global__ __launch_bounds__(256) void prep_kernel(
    const float* __restrict__ video, const float* __restrict__ fcw,
    const float* __restrict__ pw, const float* __restrict__ words,
    const float* __restrict__ cw,
    _Float16* __restrict__ videoH, _Float16* __restrict__ fcwH,
    _Float16* __restrict__ pwH, _Float16* __restrict__ wordsH,
    _Float16* __restrict__ cwH) {
  for (int u = blockIdx.x * 256 + threadIdx.x; u < PREP_C4; u += 2048 * 256) {
    if (u < PREP_C3) {
      const float* src; _Float16* dst; int off;
      if (u < PREP_C0)      { src = video; dst = videoH; off = u; }
      else if (u < PREP_C1) { src = fcw;   dst = fcwH;   off = u - PREP_C0; }
      else if (u < PREP_C2) { src = pw;    dst = pwH;    off = u - PREP_C1; }
      else                  { src = words; dst = wordsH; off = u - PREP_C2; }
      float4 v = *reinterpret_cast<const float4*>(&src[(size_t)off * 4]);
      half4v h;
      h[0] = (_Float16)v.x; h[1] = (_Float16)v.y;
      h[2] = (_Float16)v.z; h[3] = (_Float16)v.w;
      *reinterpret_cast<half4v*>(&dst[(size_t)off * 4]) = h;
    } else {
      int e = u - PREP_C3;                 // (li, o, i4)
      int li = e >> 16, rem = e & 65535, o = rem >> 7, i4 = rem & 127;
      size_t srcbase = ((size_t)(li * 512 + o) * 512 + i4 * 4) * 4;
      float4 v0 = *reinterpret_cast<const float4*>(&cw[srcbase]);
      float4 v1 = *reinterpret_cast<const float4*>(&cw[srcbase + 4]);
      float4 v2 = *reinterpret_cast<const float4*>(&cw[srcbase + 8]);
      float4 v3 = *reinterpret_cast<const float4*>(&cw[srcbase + 12]);
      size_t rb = ((size_t)(li * 512 + o)) * 2048 + i4 * 4;
      half4v h;
      h[0] = (_Float16)v0.x; h[1] = (_Float16)v1.x; h[2] = (_Float16)v2.x; h[3] = (_Float16)v3.x;
      *reinterpret_cast<half4v*>(&cwH[rb]) = h;
      h[0] = (_Float16)v0.y; h[1] = (_Float16)v1.y; h[2] = (_Float16)v2.y; h[3] = (_Float16)v3.y;
      *reinterpret_cast<half4v*>(&cwH[rb + 512]) = h;
      h[0] = (_Float16)v0.z; h[1] = (_Float16)v1.z; h[2] = (_Float16)v2.z; h[3] = (_Float16)v3.z;
      *reinterpret_cast<half4v*>(&cwH[rb + 1024]) = h;
      h[0] = (_Float16)v0.w; h[1] = (_Float16)v1.w; h[2] = (_Float16)v2.w; h[3] = (_Float16)v3.w;
      *reinterpret_cast<half4v*>(&cwH[rb + 1536]) = h;
    }
  }
}

// ---------------------------------------------------------------------------
// Merged fnorm + gram: blocks 0..31 = per-query word Gram; blocks 32..1959 =
// row L2 norms of f_all (wave per row). (No fences — R13 lesson.)
// ---------------------------------------------------------------------------
__global__ __launch_bounds__(256) void fng_kernel(
    const float* __restrict__ words, const _Float16* __restrict__ fH,
    float* __restrict__ gram, float* __restrict__ fn) {
  __shared__ float wsh[L_][513];
  const int bid = blockIdx.x, tid = threadIdx.x;
  if (bid < 32) {
    const int q = bid;
    for (int idx = tid; idx < L_ * 512; idx += 256)
      wsh[idx >> 9][idx & 511] = words[(size_t)q * L_ * J_ + idx];
    __syncthreads();
    for (int pr = tid; pr < L_ * L_; pr += 256) {
      int l = pr / L_, l2 = pr % L_;
      float sum = 0.f;
      for (int d = 0; d < J_; ++d) sum += wsh[l][d] * wsh[l2][d];
      gram[q * L_ * L_ + pr] = sum;
    }
  } else {
    const int gw = (bid - 32) * 4 + (tid >> 6);
    const int lane = tid & 63;
    if (gw >= B_ * P_) return;
    half8 h = *reinterpret_cast<const half8*>(&fH[(size_t)gw * 512 + lane * 8]);
    float s = 0.f;
    #pragma unroll
    for (int j = 0; j < 8; ++j) {
      float x = (float)h[j];
      s += x * x;
    }
    #pragma unroll
    for (int off = 32; off; off >>= 1) s += __shfl_xor(s, off);
    if (lane == 0) fn[gw] = sqrtf(s);
  }
}

// ---------------------------------------------------------------------------
// Merged sim + NMS: one block per (q,b). Threads 0..240 compute the row's
// sims (identical math/FP-order to the old sim_kernel) into LDS; positive_map
// written when q==b; then wave 0 runs the identical greedy NMS from LDS.
// Deletes the score global round-trip and one launch.
// ---------------------------------------------------------------------------
__global__ __launch_bounds__(256) void simnms_kernel(
    const float* __restrict__ logits, const float* __restrict__ gram,
    const float* __restrict__ fnorm, const float* __restrict__ iou,
    const float* __restrict__ lam, float* __restrict__ smat,
    float* __restrict__ out) {
  __shared__ float G[L_ * L_];
  __shared__ float sc[256];
  const int blk = blockIdx.x;           // q*32 + b
  const int q = blk >> 5, b = blk & 31;
  const int tid = threadIdx.x;

  for (int i = tid; i < L_ * L_; i += 256) G[i] = gram[q * L_ * L_ + i];
  __syncthreads();

  float val = NEG_;
  if (tid < P_) {
    const int r = b * P_ + tid;
    const float* lg = &logits[(size_t)r * (Q_ * L_) + q * L_];
    float raw[L_], e[L_];
    float m = -1e30f;
    #pragma unroll
    for (int l = 0; l < L_; ++l) { raw[l] = lg[l]; m = fmaxf(m, raw[l]); }
    float s = 0.f;
    #pragma unroll
    for (int l = 0; l < L_; ++l) { e[l] = __expf(raw[l] - m); s += e[l]; }
    float inv = 1.f / s;
    float fvs = 0.f;
    #pragma unroll
    for (int l = 0; l < L_; ++l) fvs += e[l] * raw[l];
    fvs *= inv;
    float vn2 = 0.f;
    for (int l = 0; l < L_; ++l) {
      float acc = 0.f;
      #pragma unroll
      for (int l2 = 0; l2 < L_; ++l2) acc += e[l2] * G[l * L_ + l2];
      vn2 += e[l] * acc;
    }
    vn2 *= inv * inv;
    float fn = fnorm[r] + 1e-8f;
    float vn = sqrtf(fmaxf(vn2, 0.f)) + 1e-8f;
    val = fvs / (fn * vn);
    if (b == q) out[1 + r] = val;       // positive_map
  }
  sc[tid] = (tid < P_) ? val : NEG_;
  __syncthreads();

  if (tid < 64) {
    const int lane = tid;
    float s[4];
    #pragma unroll
    for (int i = 0; i < 4; ++i) s[i] = sc[lane + 64 * i];
    float lamv = lam[0];
    float acc = 0.f, wgt = 1.f;
    for (int k = 0; k < 5; ++k) {
      float bv = NEG_ * 2.f; int bi = 1 << 30;
      #pragma unroll
      for (int i = 0; i < 4; ++i) {
        int p = lane + 64 * i;
        if (s[i] > bv) { bv = s[i]; bi = p; }
      }
      for (int off = 32; off; off >>= 1) {
        float ov = __shfl_xor(bv, off);
        int oi = __shfl_xor(bi, off);
        if (ov > bv || (ov == bv && oi < bi)) { bv = ov; bi = oi; }
      }
      acc += bv * wgt;
      wgt *= lamv;
      const float* irow = &iou[(size_t)bi * P_];
      #pragma unroll
      for (int i = 0; i < 4; ++i) {
        int p = lane + 64 * i;
        if (p < P_ && irow[p] > 0.7f) s[i] = NEG_;
        if (p == bi) s[i] = NEG_;
      }
    }
    if (lane == 0) smat[blk] = acc * 0.2f;
  }
}

// ---------------------------------------------------------------------------
// diag margin loss
// ---------------------------------------------------------------------------
__global__ __launch_bounds__(1024) void loss_kernel(
    const float* __restrict__ smat, float* __restrict__ out) {
  __shared__ float sm[B_][B_ + 1];
  __shared__ float red[16];
  int tid = threadIdx.x;
  sm[tid >> 5][tid & 31] = smat[tid];
  __syncthreads();
  int i = tid >> 5, j = tid & 31;
  float val = 0.f;
  if (i != j) {
    float sij = sm[i][j];
    val = fmaxf(0.f, 0.2f + sij - sm[i][i]) + fmaxf(0.f, 0.2f + sij - sm[j][j]);
  }
  #pragma unroll
  for (int off = 32; off; off >>= 1) val += __shfl_xor(val, off);
  if ((tid & 63) == 0) red[tid >> 6] = val;
  __syncthreads();
  if (tid == 0) {
    float t = 0.f;
    #pragma unroll
    for (int w = 0; w < 16; ++w) t += red[w];
    out[0] = t / 32.f;
  }
}

extern "C" void kernel_launch(void* const* d_in, const int* in_sizes, int n_in,
                              void* d_out, int out_size, void* d_ws, size_t ws_size,
                              hipStream_t stream) {
  const float* video  = (const float*)d_in[0];
  const float* words  = (const float*)d_in[1];
  // d_in[2] = w_masks: all-ones by construction, unused
  const float* lam    = (const float*)d_in[3];
  const float* iou    = (const float*)d_in[4];
  const float* fc_w   = (const float*)d_in[5];
  const float* fc_b   = (const float*)d_in[6];
  const float* conv_w = (const float*)d_in[7];
  const float* conv_b = (const float*)d_in[8];
  const float* pw     = (const float*)d_in[9];
  const float* pb     = (const float*)d_in[10];
  float* out = (float*)d_out;

  // Workspace layout (bytes) — R10 footprint (proven). Split-K partials
  // alias the logits region (written later).
  char* base = (char*)d_ws;
  _Float16* videoH= (_Float16*)(base + 0);              // 8192*1024 (16.78 MB)
  _Float16* fcoH  = (_Float16*)(base + 16777216);       // 8192*512  (8.39 MB)
  _Float16* pyrH  = (_Float16*)(base + 25165824);       // 7712*512  (7.90 MB)
  _Float16* fallH = (_Float16*)(base + 33062912);       // 7712*512  (7.90 MB)
  _Float16* cwH   = (_Float16*)(base + 40960000);       // 6*512*2048 (12.58 MB)
  _Float16* fcwH  = (_Float16*)(base + 53542912);       // 512*1024  (1.05 MB)
  _Float16* pwH   = (_Float16*)(base + 54591488);       // 512*512   (0.52 MB)
  _Float16* wordsH= (_Float16*)(base + 55115776);       // 32*20*512 (0.66 MB)
  float*    logits= (float*)(base + 55771136);          // 7712*640 f32 (19.74 MB)
  float*    part  = (float*)(base + 55771136);          //   alias, max 8.12 MB
  float*    fnorm = (float*)(base + 76500992);          // 7936 f32
  float*    gram  = (float*)(base + 76532736);          // 12800 f32
  float*    smat  = (float*)(base + 76583936);          // 1024 f32

  const int Tl[6]   = {127, 62, 30, 14, 6, 2};
  const int Poff[6] = {0, 127, 189, 219, 233, 239};

  // 0) unified operand prep (1 launch, coalesced repack)
  prep_kernel<<<2048, 256, 0, stream>>>(
      video, fc_w, pw, words, conv_w, videoH, fcwH, pwH, wordsH, cwH);

  // 1) FC: M=8192 N=512 K=1024, grid (8,128) = 1024 blocks (4/CU)
  g1p<64, 128, 0><<<dim3(8, 128), 256, 0, stream>>>(
      videoH, fcwH, fc_b, fcoH, nullptr,
      8192, 8192, 0, 0, 1, 1024, 1024, 1024, 0, 0, 0, 512);

  // 2) conv0: M=4064 K=2048, grid (8,64) = 512 blocks, direct write
  g1p<64, 128, 1><<<dim3(8, 64, 1), 256, 0, stream>>>(
      fcoH, cwH, conv_b, pyrH, nullptr,
      4064, 127, 256, 0, 2, 512, 2048, 2048, 0, P_, 0, 512);

  // 3) conv1..5: split-K partials (alias logits region) + reduce (R10 cfg)
  const int Ms[5]    = {1984, 960, 448, 192, 64};
  const int mbs[5]   = {31, 15, 7, 3, 1};
  const int kSs[5]   = {2, 4, 4, 8, 8};
  const int KLENs[5] = {1024, 512, 512, 256, 256};
  for (int i = 0; i < 5; ++i) {
    int li = i + 1;
    g1p<64, 128, 3><<<dim3(8, mbs[i], kSs[i]), 256, 0, stream>>>(
        pyrH, cwH + (size_t)li * 512 * 2048, nullptr, nullptr, part,
        Ms[i], Tl[li], P_, Poff[li - 1], 2, 512, 2048, KLENs[i], Ms[i], 0, 0, 512);
    reduce_kernel<<<Ms[i] * 2, 256, 0, stream>>>(
        part, conv_b + li * 512, pyrH, kSs[i], Ms[i], Ms[i], Tl[li], Poff[li]);
  }

  // 4) pointwise projection: M=7712 N=512 K=512, grid (8,121) = 968 blocks
  g1p<64, 128, 0><<<dim3(8, 121, 1), 256, 0, stream>>>(
      pyrH, pwH, pb, fallH, nullptr,
      B_ * P_, B_ * P_, 0, 0, 1, 512, 512, 512, 0, 0, 0, 512);

  // 5) merged gram + fnorm (1 launch)
  fng_kernel<<<1960, 256, 0, stream>>>(words, fallH, gram, fnorm);

  // 6) attention logits: N=640, grid (10,121) = 1210 blocks
  g1p<64, 128, 2><<<dim3(10, 121, 1), 256, 0, stream>>>(
      fallH, wordsH, nullptr, nullptr, logits,
      B_ * P_, B_ * P_, 0, 0, 1, 512, 512, 512, 0, 0, 0, 640);

  // 7) merged softmax+cosine-sim+NMS (+ fused positive_map), 1024 blocks
  simnms_kernel<<<1024, 256, 0, stream>>>(logits, gram, fnorm, iou, lam, smat, out);

  // 8) loss
  loss_kernel<<<1, 1024, 0, stream>>>(smat, out);
}